// Round 7
// baseline (717.588 us; speedup 1.0000x reference)
//
#include <hip/hip_runtime.h>
#include <hip/hip_bf16.h>

// ---------------------------------------------------------------------------
// GAE: 2x GCNConv (self-loops, sym-norm) + edge dot decoder.
// R5->R6b: XCD-sliced aggregation. The gather working set (h1, 25.6MB) is
// split into 8 feature slices of 32 dims (64B/row); slice = blockIdx%8 so
// (with round-robin block->XCD dispatch) each XCD's L2 only caches its own
// 3.2MB slice -> compulsory misses only. Edge records are re-read per slice
// via nontemporal 64-bit loads (uint2 class type rejected by the builtin).
// Scatter: 8 passes folded into one bucket-major launch.
// ---------------------------------------------------------------------------

#define CHUNK 512  // scan chunk
#define NPASS 8    // scatter write-window buckets

typedef __attribute__((ext_vector_type(8))) short short8;
typedef __attribute__((ext_vector_type(4))) float f32x4;

__device__ __forceinline__ unsigned short f2bf_rne(float f) {
  unsigned int b = __float_as_uint(f);
  b += 0x7FFFu + ((b >> 16) & 1u);
  return (unsigned short)(b >> 16);
}
__device__ __forceinline__ float bf_lo(unsigned int u) {
  return __uint_as_float(u << 16);
}
__device__ __forceinline__ float bf_hi(unsigned int u) {
  return __uint_as_float(u & 0xFFFF0000u);
}

__global__ void init_k(int* __restrict__ cnt, int* __restrict__ fill, int n) {
  int i = blockIdx.x * blockDim.x + threadIdx.x;
  if (i < n) { cnt[i] = 0; fill[i] = 0; }
}

__global__ void count_k(const int* __restrict__ dst, int* __restrict__ cnt, int E) {
  int i = blockIdx.x * blockDim.x + threadIdx.x;
  if (i < E) atomicAdd(&cnt[dst[i]], 1);
}

__global__ void dis_k(const int* __restrict__ cnt, float* __restrict__ dis, int n) {
  int i = blockIdx.x * blockDim.x + threadIdx.x;
  if (i < n) dis[i] = rsqrtf((float)(cnt[i] + 1));  // +1: self loop
}

__global__ void chunk_scan_k(const int* __restrict__ cnt, int* __restrict__ rp,
                             int* __restrict__ bsum, int n) {
  __shared__ int s[CHUNK];
  int t = threadIdx.x, b = blockIdx.x;
  int i = b * CHUNK + t;
  int v = (i < n) ? cnt[i] : 0;
  s[t] = v;
  __syncthreads();
  for (int off = 1; off < CHUNK; off <<= 1) {
    int u = (t >= off) ? s[t - off] : 0;
    __syncthreads();
    s[t] += u;
    __syncthreads();
  }
  if (i < n) rp[i] = s[t] - v;  // local exclusive
  if (t == CHUNK - 1) bsum[b] = s[t];
}

__global__ void scan_sums_k(int* __restrict__ bsum, int* __restrict__ rp,
                            int nchunks, int n) {
  __shared__ int s[CHUNK];
  int t = threadIdx.x;
  int v = (t < nchunks) ? bsum[t] : 0;
  s[t] = v;
  __syncthreads();
  for (int off = 1; off < CHUNK; off <<= 1) {
    int u = (t >= off) ? s[t - off] : 0;
    __syncthreads();
    s[t] += u;
    __syncthreads();
  }
  if (t < nchunks) bsum[t] = s[t] - v;  // exclusive
  if (t == nchunks - 1) rp[n] = s[t];   // grand total = E
}

__global__ void add_off_k(int* __restrict__ rp, const int* __restrict__ bsum, int n) {
  int i = blockIdx.x * CHUNK + threadIdx.x;
  if (i < n) rp[i] += bsum[blockIdx.x];
}

// single-launch bucketed scatter: blockIdx major = bucket p (dispatch order
// keeps the ~1.6MB write window temporally local in L2).
__global__ void scatter_all_k(const int* __restrict__ src, const int* __restrict__ dst,
                              const int* __restrict__ rp, int* __restrict__ fill,
                              const float* __restrict__ dis,
                              unsigned long long* __restrict__ edges,
                              int E, int EB, int n) {
  int p = blockIdx.x / EB;
  int c = blockIdx.x % EB;
  int i = c * 256 + threadIdx.x;
  if (i >= E) return;
  int lo = (int)((long long)n * p / NPASS);
  int hi = (int)((long long)n * (p + 1) / NPASS);
  int d = __builtin_nontemporal_load(&dst[i]);
  if (d < lo || d >= hi) return;
  int s = src[i];
  int pos = rp[d] + atomicAdd(&fill[d], 1);
  float w = dis[s] * dis[d];
  unsigned long long rec = (unsigned long long)(unsigned)s |
                           ((unsigned long long)__float_as_uint(w) << 32);
  edges[pos] = rec;
}

// ---- fp32 -> bf16 bulk convert (n multiple of 4) ----
__global__ void cvt_bf_k(const float* __restrict__ in, unsigned short* __restrict__ out,
                         int n4) {
  int i = blockIdx.x * blockDim.x + threadIdx.x;
  if (i >= n4) return;
  float4 v = *reinterpret_cast<const float4*>(in + (size_t)i * 4);
  unsigned int p0 = (unsigned int)f2bf_rne(v.x) | ((unsigned int)f2bf_rne(v.y) << 16);
  unsigned int p1 = (unsigned int)f2bf_rne(v.z) | ((unsigned int)f2bf_rne(v.w) << 16);
  *reinterpret_cast<uint2*>(out + (size_t)i * 4) = make_uint2(p0, p1);
}

// ---- W [K][N] fp32 -> Wt [N][K] bf16 (tiny) ----
__global__ void cvt_wt_k(const float* __restrict__ W, unsigned short* __restrict__ Wt,
                         int K, int N) {
  int i = blockIdx.x * blockDim.x + threadIdx.x;
  if (i >= K * N) return;
  int k = i / N, n = i % N;
  Wt[(size_t)n * K + k] = f2bf_rne(W[i]);
}

// ---------------- bf16 MFMA GEMM: C[M,N] = A[M,K] @ Bt[N,K]^T ---------------
#define LDST 40
__launch_bounds__(256) __global__
void bfgemm_k(const unsigned short* __restrict__ A,   // [M][K] bf16
              const unsigned short* __restrict__ Bt,  // [N][K] bf16
              unsigned short* __restrict__ C,         // [M][N] bf16
              int M, int N, int K) {
  __shared__ short As[128 * LDST];
  __shared__ short Bs[128 * LDST];
  int t = threadIdx.x;
  int lane = t & 63, wave = t >> 6;
  int quad = lane >> 4, l16 = lane & 15;
  int wm = (wave & 1) * 64, wn = (wave >> 1) * 64;
  int m0 = blockIdx.y * 128, n0 = blockIdx.x * 128;
  f32x4 acc[4][4];
#pragma unroll
  for (int i = 0; i < 4; i++)
#pragma unroll
    for (int j = 0; j < 4; j++) acc[i][j] = (f32x4)0.f;

  for (int k0 = 0; k0 < K; k0 += 32) {
    uint4 av[2], bv[2];
#pragma unroll
    for (int u = 0; u < 2; u++) {
      int idx = t + u * 256;
      int row = idx >> 2, c8 = (idx & 3) * 8;
      int gr = m0 + row;
      av[u] = make_uint4(0u, 0u, 0u, 0u);
      if (gr < M)
        av[u] = *reinterpret_cast<const uint4*>(A + (size_t)gr * K + k0 + c8);
      bv[u] = *reinterpret_cast<const uint4*>(Bt + (size_t)(n0 + row) * K + k0 + c8);
    }
    __syncthreads();
#pragma unroll
    for (int u = 0; u < 2; u++) {
      int idx = t + u * 256;
      int row = idx >> 2, c8 = (idx & 3) * 8;
      *reinterpret_cast<uint4*>(&As[row * LDST + c8]) = av[u];
      *reinterpret_cast<uint4*>(&Bs[row * LDST + c8]) = bv[u];
    }
    __syncthreads();
    short8 af[4], bfr[4];
#pragma unroll
    for (int mt = 0; mt < 4; mt++)
      af[mt] = *reinterpret_cast<const short8*>(&As[(wm + mt * 16 + l16) * LDST + quad * 8]);
#pragma unroll
    for (int nt = 0; nt < 4; nt++)
      bfr[nt] = *reinterpret_cast<const short8*>(&Bs[(wn + nt * 16 + l16) * LDST + quad * 8]);
#pragma unroll
    for (int mt = 0; mt < 4; mt++)
#pragma unroll
      for (int nt = 0; nt < 4; nt++)
        acc[mt][nt] = __builtin_amdgcn_mfma_f32_16x16x32_bf16(af[mt], bfr[nt], acc[mt][nt], 0, 0, 0);
  }
#pragma unroll
  for (int mt = 0; mt < 4; mt++) {
#pragma unroll
    for (int r = 0; r < 4; r++) {
      int grow = m0 + wm + mt * 16 + quad * 4 + r;
      if (grow >= M) continue;
      unsigned short* cp = C + (size_t)grow * N + n0 + wn + l16;
#pragma unroll
      for (int nt = 0; nt < 4; nt++) cp[nt * 16] = f2bf_rne(acc[mt][nt][r]);
    }
  }
}

// -------- XCD-sliced CSR aggregation (bf16 h, fp32 accumulate) --------------
// slice = blockIdx % NSLICE (XCD-aligned under round-robin dispatch); each
// 16-lane group handles one node's 32-dim slice (1 uint = 2 bf16 per lane).
// Edge records loaded nontemporally as u64 (streamed, keep L2 for h slice);
// out written nontemporally.
template <int DIM, int NSLICE, bool RELU, bool OBF>
__launch_bounds__(256) __global__
void agg_slice_k(const unsigned short* __restrict__ h, const int* __restrict__ rp,
                 const unsigned long long* __restrict__ edges,
                 const float* __restrict__ dis, const float* __restrict__ bias,
                 void* __restrict__ outv, int n) {
  const int PF = 4;
  int slice = blockIdx.x % NSLICE;
  int nb = blockIdx.x / NSLICE;
  int g = threadIdx.x >> 4, l = threadIdx.x & 15;
  int node = nb * 16 + g;
  if (node >= n) return;
  int off = slice * 32 + l * 2;  // dim offset, 2 dims per lane
  int start = rp[node], end = rp[node + 1];
  float di = dis[node];
  float sw = di * di;
  unsigned int hv0 = *reinterpret_cast<const unsigned int*>(h + (size_t)node * DIM + off);
  float a0 = bf_lo(hv0) * sw, a1 = bf_hi(hv0) * sw;  // self loop
  int e = start;
  for (; e + PF <= end; e += PF) {
    unsigned long long ew[PF];
    unsigned int hv[PF];
#pragma unroll
    for (int j = 0; j < PF; j++) ew[j] = __builtin_nontemporal_load(&edges[e + j]);
#pragma unroll
    for (int j = 0; j < PF; j++) {
      unsigned int s = (unsigned int)ew[j];
      hv[j] = *reinterpret_cast<const unsigned int*>(h + (size_t)s * DIM + off);
    }
#pragma unroll
    for (int j = 0; j < PF; j++) {
      float w = __uint_as_float((unsigned int)(ew[j] >> 32));
      a0 = fmaf(bf_lo(hv[j]), w, a0);
      a1 = fmaf(bf_hi(hv[j]), w, a1);
    }
  }
  for (; e < end; e++) {
    unsigned long long ew = __builtin_nontemporal_load(&edges[e]);
    float w = __uint_as_float((unsigned int)(ew >> 32));
    unsigned int s = (unsigned int)ew;
    unsigned int hv = *reinterpret_cast<const unsigned int*>(h + (size_t)s * DIM + off);
    a0 = fmaf(bf_lo(hv), w, a0);
    a1 = fmaf(bf_hi(hv), w, a1);
  }
  a0 += bias[off];
  a1 += bias[off + 1];
  if (RELU) { a0 = fmaxf(a0, 0.f); a1 = fmaxf(a1, 0.f); }
  if (OBF) {
    unsigned int p = (unsigned int)f2bf_rne(a0) | ((unsigned int)f2bf_rne(a1) << 16);
    unsigned int* op = reinterpret_cast<unsigned int*>((unsigned short*)outv + (size_t)node * DIM + off);
    __builtin_nontemporal_store(p, op);
  } else {
    float* op = (float*)outv + (size_t)node * DIM + off;
    __builtin_nontemporal_store(a0, op);
    __builtin_nontemporal_store(a1, op + 1);
  }
}

// --------------- decode: y[e] = dot(z[a], z[b]) over 128 dims ---------------
__launch_bounds__(256) __global__
void decode_k(const float* __restrict__ z, const int* __restrict__ ea,
              const int* __restrict__ eb, float* __restrict__ y, int E) {
  int wave = threadIdx.x >> 6, lane = threadIdx.x & 63;
  int e = blockIdx.x * (blockDim.x >> 6) + wave;
  if (e >= E) return;
  int a = ea[e], b = eb[e];
  const float2* za = reinterpret_cast<const float2*>(z + (size_t)a * 128);
  const float2* zb = reinterpret_cast<const float2*>(z + (size_t)b * 128);
  float2 pa = za[lane], pb = zb[lane];
  float s = pa.x * pb.x + pa.y * pb.y;
#pragma unroll
  for (int off = 32; off; off >>= 1) s += __shfl_down(s, off);
  if (lane == 0) y[e] = s;
}

extern "C" void kernel_launch(void* const* d_in, const int* in_sizes, int n_in,
                              void* d_out, int out_size, void* d_ws, size_t ws_size,
                              hipStream_t stream) {
  const float* x = (const float*)d_in[0];
  const int* ei = (const int*)d_in[1];
  const int* eli = (const int*)d_in[2];
  const float* W1 = (const float*)d_in[3];
  const float* b1 = (const float*)d_in[4];
  const float* W2 = (const float*)d_in[5];
  const float* b2 = (const float*)d_in[6];
  float* y = (float*)d_out;

  const int DIN = 256, DH = 256, DOUT = 128;
  const int n = in_sizes[0] / DIN;          // 50000
  const int E = in_sizes[1] / 2;            // 1.6M
  const int EL = in_sizes[2] / 2;           // 100k
  const int* src = ei;
  const int* dst = ei + E;
  const int* ea = eli;
  const int* eb = eli + EL;

  size_t off = 0;
  auto alloc = [&](size_t bytes) {
    void* p = (char*)d_ws + off;
    off += (bytes + 255) & ~(size_t)255;
    return p;
  };
  int nchunks = (n + CHUNK - 1) / CHUNK;
  int* cnt = (int*)alloc((size_t)n * 4);
  int* fill = (int*)alloc((size_t)n * 4);
  int* rp = (int*)alloc((size_t)(n + 1) * 4);
  int* bsum = (int*)alloc((size_t)(nchunks + 1) * 4);
  float* dis = (float*)alloc((size_t)n * 4);
  unsigned long long* edges = (unsigned long long*)alloc((size_t)E * 8);
  unsigned short* W1t = (unsigned short*)alloc((size_t)DIN * DH * 2);
  unsigned short* W2t = (unsigned short*)alloc((size_t)DH * DOUT * 2);
  unsigned short* xbf = (unsigned short*)alloc((size_t)n * DIN * 2);  // reused as h2
  unsigned short* h1 = (unsigned short*)alloc((size_t)n * DH * 2);
  unsigned short* z1b = (unsigned short*)alloc((size_t)n * DH * 2);
  float* z2 = (float*)alloc((size_t)n * DOUT * 4);
  (void)ws_size;

  // ---- graph prep ----
  init_k<<<(n + 255) / 256, 256, 0, stream>>>(cnt, fill, n);
  count_k<<<(E + 255) / 256, 256, 0, stream>>>(dst, cnt, E);
  dis_k<<<(n + 255) / 256, 256, 0, stream>>>(cnt, dis, n);
  chunk_scan_k<<<nchunks, CHUNK, 0, stream>>>(cnt, rp, bsum, n);
  scan_sums_k<<<1, CHUNK, 0, stream>>>(bsum, rp, nchunks, n);
  add_off_k<<<nchunks, CHUNK, 0, stream>>>(rp, bsum, n);
  {
    int EB = (E + 255) / 256;
    scatter_all_k<<<EB * NPASS, 256, 0, stream>>>(src, dst, rp, fill, dis, edges, E, EB, n);
  }

  // ---- converts ----
  cvt_bf_k<<<(n * DIN / 4 + 255) / 256, 256, 0, stream>>>(x, xbf, n * DIN / 4);
  cvt_wt_k<<<(DIN * DH + 255) / 256, 256, 0, stream>>>(W1, W1t, DIN, DH);
  cvt_wt_k<<<(DH * DOUT + 255) / 256, 256, 0, stream>>>(W2, W2t, DH, DOUT);

  // ---- conv1: h1 = bf16(xbf@W1) ; z1b = bf16(relu(agg(h1)+b1)) ----
  {
    dim3 grid(DH / 128, (n + 127) / 128);
    bfgemm_k<<<grid, 256, 0, stream>>>(xbf, W1t, h1, n, DH, DIN);
  }
  {
    int nb = (n + 15) / 16;
    agg_slice_k<256, 8, true, true><<<nb * 8, 256, 0, stream>>>(h1, rp, edges, dis, b1, z1b, n);
  }

  // ---- conv2: h2 = bf16(z1b@W2) ; z2 = agg(h2)+b2 (fp32) ----
  unsigned short* h2 = xbf;  // xbf dead after conv1 gemm
  {
    dim3 grid(DOUT / 128, (n + 127) / 128);
    bfgemm_k<<<grid, 256, 0, stream>>>(z1b, W2t, h2, n, DOUT, DH);
  }
  {
    int nb = (n + 15) / 16;
    agg_slice_k<128, 4, false, false><<<nb * 4, 256, 0, stream>>>(h2, rp, edges, dis, b2, z2, n);
  }

  // ---- decode ----
  decode_k<<<(EL + 3) / 4, 256, 0, stream>>>(z2, ea, eb, y, EL);
}

// Round 8
// 523.474 us; speedup vs baseline: 1.3708x; 1.3708x over previous
//
#include <hip/hip_runtime.h>
#include <hip/hip_bf16.h>

// ---------------------------------------------------------------------------
// GAE: 2x GCNConv (self-loops, sym-norm) + edge dot decoder.
// R7->R8: REVERT the XCD-sliced aggregation (R7: 64B gathers + NT edge loads
// doubled misses -> 257us). Back to R5's full-row wave-per-node aggregation.
// NEW: edge records store only src (4B); w = dis[src]*dis[dst] is factored
// as di * sum(dis[s]*h[s]) and recomputed in the epilogue -> halves the
// scatter's random-write payload and the aggregation edge stream.
// ---------------------------------------------------------------------------

#define CHUNK 512  // scan chunk
#define NPASS 8    // scatter write-window buckets

typedef __attribute__((ext_vector_type(8))) short short8;
typedef __attribute__((ext_vector_type(4))) float f32x4;

__device__ __forceinline__ unsigned short f2bf_rne(float f) {
  unsigned int b = __float_as_uint(f);
  b += 0x7FFFu + ((b >> 16) & 1u);
  return (unsigned short)(b >> 16);
}
__device__ __forceinline__ float bf_lo(unsigned int u) {
  return __uint_as_float(u << 16);
}
__device__ __forceinline__ float bf_hi(unsigned int u) {
  return __uint_as_float(u & 0xFFFF0000u);
}

__global__ void init_k(int* __restrict__ cnt, int* __restrict__ fill, int n) {
  int i = blockIdx.x * blockDim.x + threadIdx.x;
  if (i < n) { cnt[i] = 0; fill[i] = 0; }
}

__global__ void count_k(const int* __restrict__ dst, int* __restrict__ cnt, int E) {
  int i = blockIdx.x * blockDim.x + threadIdx.x;
  if (i < E) atomicAdd(&cnt[dst[i]], 1);
}

__global__ void dis_k(const int* __restrict__ cnt, float* __restrict__ dis, int n) {
  int i = blockIdx.x * blockDim.x + threadIdx.x;
  if (i < n) dis[i] = rsqrtf((float)(cnt[i] + 1));  // +1: self loop
}

__global__ void chunk_scan_k(const int* __restrict__ cnt, int* __restrict__ rp,
                             int* __restrict__ bsum, int n) {
  __shared__ int s[CHUNK];
  int t = threadIdx.x, b = blockIdx.x;
  int i = b * CHUNK + t;
  int v = (i < n) ? cnt[i] : 0;
  s[t] = v;
  __syncthreads();
  for (int off = 1; off < CHUNK; off <<= 1) {
    int u = (t >= off) ? s[t - off] : 0;
    __syncthreads();
    s[t] += u;
    __syncthreads();
  }
  if (i < n) rp[i] = s[t] - v;  // local exclusive
  if (t == CHUNK - 1) bsum[b] = s[t];
}

__global__ void scan_sums_k(int* __restrict__ bsum, int* __restrict__ rp,
                            int nchunks, int n) {
  __shared__ int s[CHUNK];
  int t = threadIdx.x;
  int v = (t < nchunks) ? bsum[t] : 0;
  s[t] = v;
  __syncthreads();
  for (int off = 1; off < CHUNK; off <<= 1) {
    int u = (t >= off) ? s[t - off] : 0;
    __syncthreads();
    s[t] += u;
    __syncthreads();
  }
  if (t < nchunks) bsum[t] = s[t] - v;  // exclusive
  if (t == nchunks - 1) rp[n] = s[t];   // grand total = E
}

__global__ void add_off_k(int* __restrict__ rp, const int* __restrict__ bsum, int n) {
  int i = blockIdx.x * CHUNK + threadIdx.x;
  if (i < n) rp[i] += bsum[blockIdx.x];
}

// single-launch bucketed scatter: blockIdx major = bucket p. Payload is now
// just src (4B) -> half the random-write bytes of the 8B record.
__global__ void scatter_all_k(const int* __restrict__ src, const int* __restrict__ dst,
                              const int* __restrict__ rp, int* __restrict__ fill,
                              unsigned int* __restrict__ edges,
                              int E, int EB, int n) {
  int p = blockIdx.x / EB;
  int c = blockIdx.x % EB;
  int i = c * 256 + threadIdx.x;
  if (i >= E) return;
  int lo = (int)((long long)n * p / NPASS);
  int hi = (int)((long long)n * (p + 1) / NPASS);
  int d = __builtin_nontemporal_load(&dst[i]);
  if (d < lo || d >= hi) return;
  int s = src[i];
  int pos = rp[d] + atomicAdd(&fill[d], 1);
  edges[pos] = (unsigned int)s;
}

// ---- fp32 -> bf16 bulk convert (n multiple of 4) ----
__global__ void cvt_bf_k(const float* __restrict__ in, unsigned short* __restrict__ out,
                         int n4) {
  int i = blockIdx.x * blockDim.x + threadIdx.x;
  if (i >= n4) return;
  float4 v = *reinterpret_cast<const float4*>(in + (size_t)i * 4);
  unsigned int p0 = (unsigned int)f2bf_rne(v.x) | ((unsigned int)f2bf_rne(v.y) << 16);
  unsigned int p1 = (unsigned int)f2bf_rne(v.z) | ((unsigned int)f2bf_rne(v.w) << 16);
  *reinterpret_cast<uint2*>(out + (size_t)i * 4) = make_uint2(p0, p1);
}

// ---- W [K][N] fp32 -> Wt [N][K] bf16 (tiny) ----
__global__ void cvt_wt_k(const float* __restrict__ W, unsigned short* __restrict__ Wt,
                         int K, int N) {
  int i = blockIdx.x * blockDim.x + threadIdx.x;
  if (i >= K * N) return;
  int k = i / N, n = i % N;
  Wt[(size_t)n * K + k] = f2bf_rne(W[i]);
}

// ---------------- bf16 MFMA GEMM: C[M,N] = A[M,K] @ Bt[N,K]^T ---------------
#define LDST 40
__launch_bounds__(256) __global__
void bfgemm_k(const unsigned short* __restrict__ A,   // [M][K] bf16
              const unsigned short* __restrict__ Bt,  // [N][K] bf16
              unsigned short* __restrict__ C,         // [M][N] bf16
              int M, int N, int K) {
  __shared__ short As[128 * LDST];
  __shared__ short Bs[128 * LDST];
  int t = threadIdx.x;
  int lane = t & 63, wave = t >> 6;
  int quad = lane >> 4, l16 = lane & 15;
  int wm = (wave & 1) * 64, wn = (wave >> 1) * 64;
  int m0 = blockIdx.y * 128, n0 = blockIdx.x * 128;
  f32x4 acc[4][4];
#pragma unroll
  for (int i = 0; i < 4; i++)
#pragma unroll
    for (int j = 0; j < 4; j++) acc[i][j] = (f32x4)0.f;

  for (int k0 = 0; k0 < K; k0 += 32) {
    uint4 av[2], bv[2];
#pragma unroll
    for (int u = 0; u < 2; u++) {
      int idx = t + u * 256;
      int row = idx >> 2, c8 = (idx & 3) * 8;
      int gr = m0 + row;
      av[u] = make_uint4(0u, 0u, 0u, 0u);
      if (gr < M)
        av[u] = *reinterpret_cast<const uint4*>(A + (size_t)gr * K + k0 + c8);
      bv[u] = *reinterpret_cast<const uint4*>(Bt + (size_t)(n0 + row) * K + k0 + c8);
    }
    __syncthreads();
#pragma unroll
    for (int u = 0; u < 2; u++) {
      int idx = t + u * 256;
      int row = idx >> 2, c8 = (idx & 3) * 8;
      *reinterpret_cast<uint4*>(&As[row * LDST + c8]) = av[u];
      *reinterpret_cast<uint4*>(&Bs[row * LDST + c8]) = bv[u];
    }
    __syncthreads();
    short8 af[4], bfr[4];
#pragma unroll
    for (int mt = 0; mt < 4; mt++)
      af[mt] = *reinterpret_cast<const short8*>(&As[(wm + mt * 16 + l16) * LDST + quad * 8]);
#pragma unroll
    for (int nt = 0; nt < 4; nt++)
      bfr[nt] = *reinterpret_cast<const short8*>(&Bs[(wn + nt * 16 + l16) * LDST + quad * 8]);
#pragma unroll
    for (int mt = 0; mt < 4; mt++)
#pragma unroll
      for (int nt = 0; nt < 4; nt++)
        acc[mt][nt] = __builtin_amdgcn_mfma_f32_16x16x32_bf16(af[mt], bfr[nt], acc[mt][nt], 0, 0, 0);
  }
#pragma unroll
  for (int mt = 0; mt < 4; mt++) {
#pragma unroll
    for (int r = 0; r < 4; r++) {
      int grow = m0 + wm + mt * 16 + quad * 4 + r;
      if (grow >= M) continue;
      unsigned short* cp = C + (size_t)grow * N + n0 + wn + l16;
#pragma unroll
      for (int nt = 0; nt < 4; nt++) cp[nt * 16] = f2bf_rne(acc[mt][nt][r]);
    }
  }
}

// ------------- CSR aggregation over bf16 h: fp32 accumulate ----------------
// out[d] = di * ( sum_e dis[s_e]*h[s_e] + di*h[d] ) + b
// One wave per node, full row (512B/256B coalesced gathers), PF=8 pipeline.
// edges[e] = src only; dis[s] is a wave-uniform L2-resident load.
template <int VEC, bool RELU, bool OBF>
__launch_bounds__(256) __global__
void aggregate_k(const unsigned short* __restrict__ h, const int* __restrict__ rp,
                 const unsigned int* __restrict__ edges, const float* __restrict__ dis,
                 const float* __restrict__ bias, void* __restrict__ outv, int n) {
  const int DIM = VEC * 64;
  const int PF = 8;
  int wave = threadIdx.x >> 6, lane = threadIdx.x & 63;
  int node = blockIdx.x * (blockDim.x >> 6) + wave;
  if (node >= n) return;
  int start = rp[node], end = rp[node + 1];
  float di = dis[node];
  float acc[VEC];
  {  // self loop contributes di*h[node] to the inner sum
    const unsigned short* hp = h + (size_t)node * DIM + lane * VEC;
    if (VEC == 4) {
      uint2 r = *reinterpret_cast<const uint2*>(hp);
      acc[0] = bf_lo(r.x) * di; acc[1] = bf_hi(r.x) * di;
      acc[2] = bf_lo(r.y) * di; acc[3] = bf_hi(r.y) * di;
    } else {
      unsigned int r = *reinterpret_cast<const unsigned int*>(hp);
      acc[0] = bf_lo(r) * di; acc[1] = bf_hi(r) * di;
    }
  }
  int e = start;
  for (; e + PF <= end; e += PF) {
    unsigned int s[PF];
    float w[PF];
#pragma unroll
    for (int j = 0; j < PF; j++) s[j] = __builtin_nontemporal_load(&edges[e + j]);
#pragma unroll
    for (int j = 0; j < PF; j++) w[j] = dis[s[j]];
    if (VEC == 4) {
      uint2 r[PF];
#pragma unroll
      for (int j = 0; j < PF; j++)
        r[j] = *reinterpret_cast<const uint2*>(h + (size_t)s[j] * DIM + lane * 4);
#pragma unroll
      for (int j = 0; j < PF; j++) {
        acc[0] = fmaf(bf_lo(r[j].x), w[j], acc[0]);
        acc[1] = fmaf(bf_hi(r[j].x), w[j], acc[1]);
        acc[2] = fmaf(bf_lo(r[j].y), w[j], acc[2]);
        acc[3] = fmaf(bf_hi(r[j].y), w[j], acc[3]);
      }
    } else {
      unsigned int r[PF];
#pragma unroll
      for (int j = 0; j < PF; j++)
        r[j] = *reinterpret_cast<const unsigned int*>(h + (size_t)s[j] * DIM + lane * 2);
#pragma unroll
      for (int j = 0; j < PF; j++) {
        acc[0] = fmaf(bf_lo(r[j]), w[j], acc[0]);
        acc[1] = fmaf(bf_hi(r[j]), w[j], acc[1]);
      }
    }
  }
  for (; e < end; e++) {
    unsigned int s = edges[e];
    float w = dis[s];
    const unsigned short* hs = h + (size_t)s * DIM + lane * VEC;
    if (VEC == 4) {
      uint2 r = *reinterpret_cast<const uint2*>(hs);
      acc[0] = fmaf(bf_lo(r.x), w, acc[0]);
      acc[1] = fmaf(bf_hi(r.x), w, acc[1]);
      acc[2] = fmaf(bf_lo(r.y), w, acc[2]);
      acc[3] = fmaf(bf_hi(r.y), w, acc[3]);
    } else {
      unsigned int r = *reinterpret_cast<const unsigned int*>(hs);
      acc[0] = fmaf(bf_lo(r), w, acc[0]);
      acc[1] = fmaf(bf_hi(r), w, acc[1]);
    }
  }
#pragma unroll
  for (int v = 0; v < VEC; v++) {
    float r = fmaf(di, acc[v], bias[lane * VEC + v]);
    if (RELU) r = fmaxf(r, 0.f);
    acc[v] = r;
  }
  if (OBF) {
    unsigned short* op = (unsigned short*)outv + (size_t)node * DIM + lane * VEC;
    if (VEC == 4) {
      unsigned int p0 = (unsigned int)f2bf_rne(acc[0]) | ((unsigned int)f2bf_rne(acc[1]) << 16);
      unsigned int p1 = (unsigned int)f2bf_rne(acc[2]) | ((unsigned int)f2bf_rne(acc[3]) << 16);
      *reinterpret_cast<uint2*>(op) = make_uint2(p0, p1);
    } else {
      unsigned int p0 = (unsigned int)f2bf_rne(acc[0]) | ((unsigned int)f2bf_rne(acc[1]) << 16);
      *reinterpret_cast<unsigned int*>(op) = p0;
    }
  } else {
    float* op = (float*)outv + (size_t)node * DIM + lane * VEC;
#pragma unroll
    for (int v = 0; v < VEC; v++) op[v] = acc[v];
  }
}

// --------------- decode: y[e] = dot(z[a], z[b]) over 128 dims ---------------
__launch_bounds__(256) __global__
void decode_k(const float* __restrict__ z, const int* __restrict__ ea,
              const int* __restrict__ eb, float* __restrict__ y, int E) {
  int wave = threadIdx.x >> 6, lane = threadIdx.x & 63;
  int e = blockIdx.x * (blockDim.x >> 6) + wave;
  if (e >= E) return;
  int a = ea[e], b = eb[e];
  const float2* za = reinterpret_cast<const float2*>(z + (size_t)a * 128);
  const float2* zb = reinterpret_cast<const float2*>(z + (size_t)b * 128);
  float2 pa = za[lane], pb = zb[lane];
  float s = pa.x * pb.x + pa.y * pb.y;
#pragma unroll
  for (int off = 32; off; off >>= 1) s += __shfl_down(s, off);
  if (lane == 0) y[e] = s;
}

extern "C" void kernel_launch(void* const* d_in, const int* in_sizes, int n_in,
                              void* d_out, int out_size, void* d_ws, size_t ws_size,
                              hipStream_t stream) {
  const float* x = (const float*)d_in[0];
  const int* ei = (const int*)d_in[1];
  const int* eli = (const int*)d_in[2];
  const float* W1 = (const float*)d_in[3];
  const float* b1 = (const float*)d_in[4];
  const float* W2 = (const float*)d_in[5];
  const float* b2 = (const float*)d_in[6];
  float* y = (float*)d_out;

  const int DIN = 256, DH = 256, DOUT = 128;
  const int n = in_sizes[0] / DIN;          // 50000
  const int E = in_sizes[1] / 2;            // 1.6M
  const int EL = in_sizes[2] / 2;           // 100k
  const int* src = ei;
  const int* dst = ei + E;
  const int* ea = eli;
  const int* eb = eli + EL;

  size_t off = 0;
  auto alloc = [&](size_t bytes) {
    void* p = (char*)d_ws + off;
    off += (bytes + 255) & ~(size_t)255;
    return p;
  };
  int nchunks = (n + CHUNK - 1) / CHUNK;
  int* cnt = (int*)alloc((size_t)n * 4);
  int* fill = (int*)alloc((size_t)n * 4);
  int* rp = (int*)alloc((size_t)(n + 1) * 4);
  int* bsum = (int*)alloc((size_t)(nchunks + 1) * 4);
  float* dis = (float*)alloc((size_t)n * 4);
  unsigned int* edges = (unsigned int*)alloc((size_t)E * 4);  // src only
  unsigned short* W1t = (unsigned short*)alloc((size_t)DIN * DH * 2);
  unsigned short* W2t = (unsigned short*)alloc((size_t)DH * DOUT * 2);
  unsigned short* xbf = (unsigned short*)alloc((size_t)n * DIN * 2);  // reused as h2
  unsigned short* h1 = (unsigned short*)alloc((size_t)n * DH * 2);
  unsigned short* z1b = (unsigned short*)alloc((size_t)n * DH * 2);
  float* z2 = (float*)alloc((size_t)n * DOUT * 4);
  (void)ws_size;

  // ---- graph prep ----
  init_k<<<(n + 255) / 256, 256, 0, stream>>>(cnt, fill, n);
  count_k<<<(E + 255) / 256, 256, 0, stream>>>(dst, cnt, E);
  dis_k<<<(n + 255) / 256, 256, 0, stream>>>(cnt, dis, n);
  chunk_scan_k<<<nchunks, CHUNK, 0, stream>>>(cnt, rp, bsum, n);
  scan_sums_k<<<1, CHUNK, 0, stream>>>(bsum, rp, nchunks, n);
  add_off_k<<<nchunks, CHUNK, 0, stream>>>(rp, bsum, n);
  {
    int EB = (E + 255) / 256;
    scatter_all_k<<<EB * NPASS, 256, 0, stream>>>(src, dst, rp, fill, edges, E, EB, n);
  }

  // ---- converts ----
  cvt_bf_k<<<(n * DIN / 4 + 255) / 256, 256, 0, stream>>>(x, xbf, n * DIN / 4);
  cvt_wt_k<<<(DIN * DH + 255) / 256, 256, 0, stream>>>(W1, W1t, DIN, DH);
  cvt_wt_k<<<(DH * DOUT + 255) / 256, 256, 0, stream>>>(W2, W2t, DH, DOUT);

  // ---- conv1: h1 = bf16(xbf@W1) ; z1b = bf16(relu(agg(h1)+b1)) ----
  {
    dim3 grid(DH / 128, (n + 127) / 128);
    bfgemm_k<<<grid, 256, 0, stream>>>(xbf, W1t, h1, n, DH, DIN);
  }
  aggregate_k<4, true, true><<<(n + 3) / 4, 256, 0, stream>>>(h1, rp, edges, dis, b1, z1b, n);

  // ---- conv2: h2 = bf16(z1b@W2) ; z2 = agg(h2)+b2 (fp32) ----
  unsigned short* h2 = xbf;  // xbf dead after conv1 gemm
  {
    dim3 grid(DOUT / 128, (n + 127) / 128);
    bfgemm_k<<<grid, 256, 0, stream>>>(z1b, W2t, h2, n, DOUT, DH);
  }
  aggregate_k<2, false, false><<<(n + 3) / 4, 256, 0, stream>>>(h2, rp, edges, dis, b2, z2, n);

  // ---- decode ----
  decode_k<<<(EL + 3) / 4, 256, 0, stream>>>(z2, ea, eb, y, EL);
}